// Round 14
// baseline (83.073 us; speedup 1.0000x reference)
//
#include <hip/hip_runtime.h>
#include <hip/hip_bf16.h>

// CARAFE++ downsample: B=8, C=128, H=W=160, stride 2 -> HD=WD=80
// R13 lesson: kls-in-global = 24.6M redundant VMEM insts (issue wall);
// R11 lesson: kls-in-LDS with c-fastest lanes = 14.4M bank conflicts.
// v4 = R11 LDS layout + v3 q-fastest lane map: conflict-free LDS kls,
// no redundant VMEM. 34.7KB LDS -> 4 blocks/CU.
#define B   8
#define C   128
#define H   160
#define W   160
#define HW  (H*W)       // 25600
#define CM  16
#define KC  25
#define HD  80
#define WD  80
#define HWD (HD*WD)     // 6400

typedef __fp16 half2_t __attribute__((ext_vector_type(2)));
union H2U { uint u; half2_t h; };

static __device__ __forceinline__ float dot2f(uint a, uint b, float c) {
    H2U ua, ub; ua.u = a; ub.u = b;
#if __has_builtin(__builtin_amdgcn_fdot2)
    return __builtin_amdgcn_fdot2(ua.h, ub.h, c, false);
#else
    return fmaf((float)ua.h.x, (float)ub.h.x, fmaf((float)ua.h.y, (float)ub.h.y, c));
#endif
}
static __device__ __forceinline__ uint pk16(float a, float b) {
    H2U r; r.h = __builtin_amdgcn_cvt_pkrtz(a, b); return r.u;
}

// ---- stage 1: 1x1 conv 128->16 (at HBM floor ~17.6us, unchanged) ----
__global__ __launch_bounds__(256) void compress_k(const float* __restrict__ x,
                                                  const float* __restrict__ wc,
                                                  __hip_bfloat16* __restrict__ comp) {
    __shared__ float4 red[2][CM][64];               // 32 KB
    int lane = threadIdx.x & 63;
    int s    = __builtin_amdgcn_readfirstlane(threadIdx.x >> 6);  // wave id 0..3
    int gq   = blockIdx.x * 64 + lane;              // global pixel-quad
    int px0  = gq * 4;
    int b    = px0 / HW;
    int pos  = px0 % HW;
    const float* xb = x + (size_t)b * C * HW + pos;

    float4 acc[CM];
#pragma unroll
    for (int co = 0; co < CM; ++co) acc[co] = make_float4(0.f, 0.f, 0.f, 0.f);
#pragma unroll
    for (int g = 0; g < 2; ++g) {
        float4 v[16];
#pragma unroll
        for (int u = 0; u < 16; ++u) {              // 16 f4 loads in flight
            int ci = s * 32 + g * 16 + u;
            v[u] = *reinterpret_cast<const float4*>(xb + (size_t)ci * HW);
        }
#pragma unroll
        for (int u = 0; u < 16; ++u) {
            int ci = s * 32 + g * 16 + u;
#pragma unroll
            for (int co = 0; co < CM; ++co) {
                float wv = wc[co * C + ci];         // uniform -> s_load
                acc[co].x = fmaf(v[u].x, wv, acc[co].x);
                acc[co].y = fmaf(v[u].y, wv, acc[co].y);
                acc[co].z = fmaf(v[u].z, wv, acc[co].z);
                acc[co].w = fmaf(v[u].w, wv, acc[co].w);
            }
        }
    }
    if (s >= 2) {
#pragma unroll
        for (int co = 0; co < CM; ++co) red[s - 2][co][lane] = acc[co];
    }
    __syncthreads();
    if (s < 2) {
#pragma unroll
        for (int co = 0; co < CM; ++co) {
            float4 r = red[s][co][lane];
            acc[co].x += r.x; acc[co].y += r.y; acc[co].z += r.z; acc[co].w += r.w;
        }
    }
    __syncthreads();
    if (s == 1) {
#pragma unroll
        for (int co = 0; co < CM; ++co) red[0][co][lane] = acc[co];
    }
    __syncthreads();
    if (s == 0) {
        __hip_bfloat16* cb = comp + (size_t)b * CM * HW + pos;
#pragma unroll
        for (int co = 0; co < CM; ++co) {
            float4 r = red[0][co][lane];
            float4 a = acc[co];
            union { __hip_bfloat16 h[4]; uint2 u; } pk;
            pk.h[0] = __float2bfloat16(a.x + r.x);
            pk.h[1] = __float2bfloat16(a.y + r.y);
            pk.h[2] = __float2bfloat16(a.z + r.z);
            pk.h[3] = __float2bfloat16(a.w + r.w);
            *reinterpret_cast<uint2*>(cb + co * HW) = pk.u;   // 8B store
        }
    }
}

// ---- stage 2: 3x3 s2 conv 16->25 + softmax; ker_g layout: [b][hq=20]
// [slot=15][px=320] u32 f16 tap-pairs (slot = i*3+jp; jp=2 pairs tap4,0) ----
__global__ __launch_bounds__(256) void encoder_k(const __hip_bfloat16* __restrict__ comp,
                                                 const float* __restrict__ we,
                                                 uint* __restrict__ ker_g) {
    __shared__ float part[4][KC][65];
    int lane = threadIdx.x & 63;
    int sub  = __builtin_amdgcn_readfirstlane(threadIdx.x >> 6);  // wave id, uniform
    int p  = blockIdx.x * 64 + lane;                // global pixel 0..51199
    int b  = p / HWD;
    int r2 = p % HWD;
    int hd = r2 / WD;
    int wd = r2 % WD;
    const __hip_bfloat16* cb = comp + (size_t)b * CM * HW;
    float acc[KC];
#pragma unroll
    for (int ko = 0; ko < KC; ++ko) acc[ko] = 0.f;
#pragma unroll
    for (int cii = 0; cii < 4; ++cii) {
        int ci = sub * 4 + cii;                     // uniform -> we stays s_load
#pragma unroll
        for (int kh = 0; kh < 3; ++kh) {
            int r    = 2 * hd + kh - 1;
            bool rok = (unsigned)r < H;
            int rc   = min(max(r, 0), H - 1);
#pragma unroll
            for (int kw = 0; kw < 3; ++kw) {
                int c0  = 2 * wd + kw - 1;
                bool ok = rok && ((unsigned)c0 < W);
                int cc  = min(max(c0, 0), W - 1);
                float cv = __bfloat162float(cb[(size_t)ci * HW + rc * W + cc]);
                cv = ok ? cv : 0.f;
#pragma unroll
                for (int ko = 0; ko < KC; ++ko)
                    acc[ko] = fmaf(cv, we[((ko * CM + ci) * 3 + kh) * 3 + kw], acc[ko]);
            }
        }
    }
#pragma unroll
    for (int ko = 0; ko < KC; ++ko) part[sub][ko][lane] = acc[ko];
    __syncthreads();
    if (threadIdx.x < 64) {
        float a[KC];
#pragma unroll
        for (int ko = 0; ko < KC; ++ko)
            a[ko] = (part[0][ko][lane] + part[1][ko][lane]) +
                    (part[2][ko][lane] + part[3][ko][lane]);
        float m = a[0];
#pragma unroll
        for (int ko = 1; ko < KC; ++ko) m = fmaxf(m, a[ko]);
        float s = 0.f;
#pragma unroll
        for (int ko = 0; ko < KC; ++ko) { a[ko] = __expf(a[ko] - m); s += a[ko]; }
        float inv = 1.f / s;
#pragma unroll
        for (int ko = 0; ko < KC; ++ko) part[0][ko][lane] = a[ko] * inv;
    }
    __syncthreads();
    // paired-f16 store: block's 64 pixels lie inside ONE 320-pixel hq-group
    int P0  = blockIdx.x * 64;
    int bb  = P0 / HWD;
    int rem = P0 % HWD;
    int hq  = rem / 320;
    int pl0 = rem % 320;
    uint* kout = ker_g + ((size_t)(bb * 20 + hq) * 15) * 320 + pl0;
    for (int t = threadIdx.x; t < 64 * 15; t += 256) {
        int slot = t / 64, pix = t % 64;
        int i = slot / 3, jp = slot % 3;
        int t0 = i * 5 + jp * 2;
        float k0 = part[0][t0][pix];
        float k1 = (jp < 2) ? part[0][t0 + 1][pix] : 0.f;
        kout[slot * 320 + pix] = pk16(k0, k1);      // coalesced 4B
    }
}

// ---- stage 3: 5x5 s2 reassembly v4 = R11 LDS layout + q-fastest lanes.
// Block = (b, hq: 4 out rows, cg: 4 ch), 320 thr. xls[4][11][88] 15.5KB +
// kls[15][320] 19.2KB = 34.7KB -> 4 blocks/CU. tid = c*80+hd*20+q:
// consecutive lanes -> consecutive 16B in BOTH kls and xls (conflict-free),
// out stores coalesced. Per-thread: 25 LDS b128 + ~7 VMEM. ----
__global__ __launch_bounds__(320) void reassemble_k(const float* __restrict__ x,
                                                    const uint* __restrict__ ker_g,
                                                    float* __restrict__ out) {
    __shared__ uint xls[4][11][88];                 // f16 pairs per row
    __shared__ uint kls[15][320];                   // tap-pair major
    int bid = blockIdx.x;
    int cg  = bid & 31;                             // channel group (4 ch)
    int t2  = bid >> 5;
    int hq  = t2 % 20;                              // 4-row output block
    int b   = t2 / 20;

    // stage x: 4 ch x 11 rows x 42 f4 -> f16 (lds col = gcol+4; OOB = 0)
    for (int t = threadIdx.x; t < 1848; t += 320) {
        int ch  = t / 462;                          // 462 = 11*42
        int r   = t % 462;
        int row = r / 42, f = r % 42;
        int gr  = hq * 8 - 2 + row;
        float4 v = make_float4(0.f, 0.f, 0.f, 0.f);
        if (f >= 1 && f <= 40 && (unsigned)gr < H)
            v = *reinterpret_cast<const float4*>(
                x + (size_t)(b * C + cg * 4 + ch) * HW + gr * W + (f - 1) * 4);
        uint2 hv = make_uint2(pk16(v.x, v.y), pk16(v.z, v.w));
        *reinterpret_cast<uint2*>(&xls[ch][row][f * 2]) = hv;   // 8B aligned
    }
    // stage ker: 15*320 u32 = 1200 uint4, lane-contiguous
    {
        const uint4* kg4 = reinterpret_cast<const uint4*>(
            ker_g + ((size_t)(b * 20 + hq) * 15) * 320);
        uint4* kl4 = reinterpret_cast<uint4*>(&kls[0][0]);
        for (int t = threadIdx.x; t < 1200; t += 320)
            kl4[t] = kg4[t];
    }
    __syncthreads();

    // compute: tid = c*80 + hd*20 + q -> 4 outputs (wd = 4q..4q+3), 1 ch
    int q  = threadIdx.x % 20;
    int t3 = threadIdx.x / 20;                      // 0..15
    int hd = t3 & 3;
    int c  = t3 >> 2;                               // 0..3
    int px0 = hd * 80 + 4 * q;                      // local pixel of output 0
    float a0 = 0.f, a1 = 0.f, a2 = 0.f, a3 = 0.f;
#pragma unroll
    for (int i = 0; i < 5; ++i) {
        int lr = 2 * hd + i;
        const uint* xrow = &xls[c][lr][4 * q];
        uint4 xa = *reinterpret_cast<const uint4*>(xrow);       // 16B aligned
        uint4 xb = *reinterpret_cast<const uint4*>(xrow + 4);
        uint xd[8] = {xa.x, xa.y, xa.z, xa.w, xb.x, xb.y, xb.z, xb.w};
        uint4 k0 = *reinterpret_cast<const uint4*>(&kls[i * 3 + 0][px0]);
        uint4 k1 = *reinterpret_cast<const uint4*>(&kls[i * 3 + 1][px0]);
        uint4 k2 = *reinterpret_cast<const uint4*>(&kls[i * 3 + 2][px0]);
        a0 = dot2f(xd[1], k0.x, a0); a0 = dot2f(xd[2], k1.x, a0); a0 = dot2f(xd[3], k2.x, a0);
        a1 = dot2f(xd[2], k0.y, a1); a1 = dot2f(xd[3], k1.y, a1); a1 = dot2f(xd[4], k2.y, a1);
        a2 = dot2f(xd[3], k0.z, a2); a2 = dot2f(xd[4], k1.z, a2); a2 = dot2f(xd[5], k2.z, a2);
        a3 = dot2f(xd[4], k0.w, a3); a3 = dot2f(xd[5], k1.w, a3); a3 = dot2f(xd[6], k2.w, a3);
    }
    *reinterpret_cast<float4*>(
        out + ((size_t)(b * C + cg * 4 + c) * HD + hq * 4 + hd) * WD + 4 * q) =
        make_float4(a0, a1, a2, a3);
}

extern "C" void kernel_launch(void* const* d_in, const int* in_sizes, int n_in,
                              void* d_out, int out_size, void* d_ws, size_t ws_size,
                              hipStream_t stream) {
    const float* x  = (const float*)d_in[0];
    const float* wc = (const float*)d_in[1];
    const float* we = (const float*)d_in[2];
    float* out = (float*)d_out;
    __hip_bfloat16* comp = (__hip_bfloat16*)d_ws;         // B*CM*HW bf16 = 6.55 MB
    uint* ker_g = (uint*)((char*)d_ws + (size_t)B * CM * HW * sizeof(__hip_bfloat16));
                                                          // B*20*15*320 u32 = 6.14 MB

    compress_k  <<<(B * HW / 4) / 64, 256, 0, stream>>>(x, wc, comp);    // 800 blocks
    encoder_k   <<<(B * HWD) / 64,    256, 0, stream>>>(comp, we, ker_g);// 800 blocks
    reassemble_k<<<B * 20 * 32,       320, 0, stream>>>(x, ker_g, out);  // 5120 blocks
}

// Round 15
// 71.432 us; speedup vs baseline: 1.1630x; 1.1630x over previous
//
#include <hip/hip_runtime.h>
#include <hip/hip_bf16.h>

// CARAFE++ downsample: B=8, C=128, H=W=160, stride 2 -> HD=WD=80
// RESTORED R13 v3 (measured best: 72.6us).
// Structure: compress f4+4-wave-split (HBM floor ~17.6us) -> encoder f16
// tap-pair ker (640px groups) -> reassemble: 8-row tiles, xls f16 in LDS
// (26.75KB, 30 waves/CU), ker read from GLOBAL coalesced (wave-uniform c,
// L2-hot), q-fastest lane map, dot2 compute.
#define B   8
#define C   128
#define H   160
#define W   160
#define HW  (H*W)       // 25600
#define CM  16
#define KC  25
#define HD  80
#define WD  80
#define HWD (HD*WD)     // 6400

typedef __fp16 half2_t __attribute__((ext_vector_type(2)));
union H2U { uint u; half2_t h; };

static __device__ __forceinline__ float dot2f(uint a, uint b, float c) {
    H2U ua, ub; ua.u = a; ub.u = b;
#if __has_builtin(__builtin_amdgcn_fdot2)
    return __builtin_amdgcn_fdot2(ua.h, ub.h, c, false);
#else
    return fmaf((float)ua.h.x, (float)ub.h.x, fmaf((float)ua.h.y, (float)ub.h.y, c));
#endif
}
static __device__ __forceinline__ uint pk16(float a, float b) {
    H2U r; r.h = __builtin_amdgcn_cvt_pkrtz(a, b); return r.u;
}

// ---- stage 1: 1x1 conv 128->16. Thread = 4 pixels (float4); ci split
// across 4 waves; f4 LDS reduce. ----
__global__ __launch_bounds__(256) void compress_k(const float* __restrict__ x,
                                                  const float* __restrict__ wc,
                                                  __hip_bfloat16* __restrict__ comp) {
    __shared__ float4 red[2][CM][64];               // 32 KB
    int lane = threadIdx.x & 63;
    int s    = __builtin_amdgcn_readfirstlane(threadIdx.x >> 6);  // wave id 0..3
    int gq   = blockIdx.x * 64 + lane;              // global pixel-quad
    int px0  = gq * 4;
    int b    = px0 / HW;
    int pos  = px0 % HW;
    const float* xb = x + (size_t)b * C * HW + pos;

    float4 acc[CM];
#pragma unroll
    for (int co = 0; co < CM; ++co) acc[co] = make_float4(0.f, 0.f, 0.f, 0.f);
#pragma unroll
    for (int g = 0; g < 2; ++g) {
        float4 v[16];
#pragma unroll
        for (int u = 0; u < 16; ++u) {              // 16 f4 loads in flight
            int ci = s * 32 + g * 16 + u;
            v[u] = *reinterpret_cast<const float4*>(xb + (size_t)ci * HW);
        }
#pragma unroll
        for (int u = 0; u < 16; ++u) {
            int ci = s * 32 + g * 16 + u;
#pragma unroll
            for (int co = 0; co < CM; ++co) {
                float wv = wc[co * C + ci];         // uniform -> s_load
                acc[co].x = fmaf(v[u].x, wv, acc[co].x);
                acc[co].y = fmaf(v[u].y, wv, acc[co].y);
                acc[co].z = fmaf(v[u].z, wv, acc[co].z);
                acc[co].w = fmaf(v[u].w, wv, acc[co].w);
            }
        }
    }
    if (s >= 2) {
#pragma unroll
        for (int co = 0; co < CM; ++co) red[s - 2][co][lane] = acc[co];
    }
    __syncthreads();
    if (s < 2) {
#pragma unroll
        for (int co = 0; co < CM; ++co) {
            float4 r = red[s][co][lane];
            acc[co].x += r.x; acc[co].y += r.y; acc[co].z += r.z; acc[co].w += r.w;
        }
    }
    __syncthreads();
    if (s == 1) {
#pragma unroll
        for (int co = 0; co < CM; ++co) red[0][co][lane] = acc[co];
    }
    __syncthreads();
    if (s == 0) {
        __hip_bfloat16* cb = comp + (size_t)b * CM * HW + pos;
#pragma unroll
        for (int co = 0; co < CM; ++co) {
            float4 r = red[0][co][lane];
            float4 a = acc[co];
            union { __hip_bfloat16 h[4]; uint2 u; } pk;
            pk.h[0] = __float2bfloat16(a.x + r.x);
            pk.h[1] = __float2bfloat16(a.y + r.y);
            pk.h[2] = __float2bfloat16(a.z + r.z);
            pk.h[3] = __float2bfloat16(a.w + r.w);
            *reinterpret_cast<uint2*>(cb + co * HW) = pk.u;   // 8B store
        }
    }
}

// ---- stage 2: 3x3 s2 conv 16->25 + softmax; ci split across 4 waves.
// Output ker_g layout: [b][hq=10][slot=15][px=640] u32 (f16 tap-pairs,
// slot = i*3+jp; jp=2 pairs (tap j=4, 0)). 8-row pixel groups. ----
__global__ __launch_bounds__(256) void encoder_k(const __hip_bfloat16* __restrict__ comp,
                                                 const float* __restrict__ we,
                                                 uint* __restrict__ ker_g) {
    __shared__ float part[4][KC][65];
    int lane = threadIdx.x & 63;
    int sub  = __builtin_amdgcn_readfirstlane(threadIdx.x >> 6);  // wave id, uniform
    int p  = blockIdx.x * 64 + lane;                // global pixel 0..51199
    int b  = p / HWD;
    int r2 = p % HWD;
    int hd = r2 / WD;
    int wd = r2 % WD;
    const __hip_bfloat16* cb = comp + (size_t)b * CM * HW;
    float acc[KC];
#pragma unroll
    for (int ko = 0; ko < KC; ++ko) acc[ko] = 0.f;
#pragma unroll
    for (int cii = 0; cii < 4; ++cii) {
        int ci = sub * 4 + cii;                     // uniform -> we stays s_load
#pragma unroll
        for (int kh = 0; kh < 3; ++kh) {
            int r    = 2 * hd + kh - 1;
            bool rok = (unsigned)r < H;
            int rc   = min(max(r, 0), H - 1);
#pragma unroll
            for (int kw = 0; kw < 3; ++kw) {
                int c0  = 2 * wd + kw - 1;
                bool ok = rok && ((unsigned)c0 < W);
                int cc  = min(max(c0, 0), W - 1);
                float cv = __bfloat162float(cb[(size_t)ci * HW + rc * W + cc]);
                cv = ok ? cv : 0.f;
#pragma unroll
                for (int ko = 0; ko < KC; ++ko)
                    acc[ko] = fmaf(cv, we[((ko * CM + ci) * 3 + kh) * 3 + kw], acc[ko]);
            }
        }
    }
#pragma unroll
    for (int ko = 0; ko < KC; ++ko) part[sub][ko][lane] = acc[ko];
    __syncthreads();
    if (threadIdx.x < 64) {
        float a[KC];
#pragma unroll
        for (int ko = 0; ko < KC; ++ko)
            a[ko] = (part[0][ko][lane] + part[1][ko][lane]) +
                    (part[2][ko][lane] + part[3][ko][lane]);
        float m = a[0];
#pragma unroll
        for (int ko = 1; ko < KC; ++ko) m = fmaxf(m, a[ko]);
        float s = 0.f;
#pragma unroll
        for (int ko = 0; ko < KC; ++ko) { a[ko] = __expf(a[ko] - m); s += a[ko]; }
        float inv = 1.f / s;
#pragma unroll
        for (int ko = 0; ko < KC; ++ko) part[0][ko][lane] = a[ko] * inv;
    }
    __syncthreads();
    // paired-f16 store: block's 64 pixels lie inside ONE 640-pixel hq-group
    int P0  = blockIdx.x * 64;
    int bb  = P0 / HWD;
    int rem = P0 % HWD;
    int hq  = rem / 640;
    int pl0 = rem % 640;
    uint* kout = ker_g + ((size_t)(bb * 10 + hq) * 15) * 640 + pl0;
    for (int t = threadIdx.x; t < 64 * 15; t += 256) {
        int slot = t / 64, pix = t % 64;
        int i = slot / 3, jp = slot % 3;
        int t0 = i * 5 + jp * 2;
        float k0 = part[0][t0][pix];
        float k1 = (jp < 2) ? part[0][t0 + 1][pix] : 0.f;
        kout[slot * 640 + pix] = pk16(k0, k1);      // coalesced 4B
    }
}

// ---- stage 3: 5x5 s2 reassembly v3. Block = (b, hq: 8 out rows, cg: 4 ch),
// 640 threads. xls f16 [4][19][88] = 26.75KB (only LDS use). kls read from
// GLOBAL (coalesced 16B, L2-hot, broadcast over c). lane = q fastest ->
// xls reads 2-way max (free), kls/out fully coalesced. ----
__global__ __launch_bounds__(640) void reassemble_k(const float* __restrict__ x,
                                                    const uint* __restrict__ ker_g,
                                                    float* __restrict__ out) {
    __shared__ uint xls[4][19][88];                 // f16 pairs; uint u = gcols (2u-4, 2u-3)
    int bid = blockIdx.x;
    int cg  = bid & 31;                             // channel group (4 ch)
    int t2  = bid >> 5;
    int hq  = t2 % 10;                              // 8-row output block
    int b   = t2 / 10;

    // stage x: 4 ch x 19 rows x 42 f4 -> f16 (lds col = gcol+4; OOB = 0)
    for (int t = threadIdx.x; t < 3192; t += 640) {
        int ch  = t / 798;                          // 798 = 19*42
        int r   = t % 798;
        int row = r / 42, f = r % 42;
        int gr  = hq * 16 - 2 + row;
        float4 v = make_float4(0.f, 0.f, 0.f, 0.f);
        if (f >= 1 && f <= 40 && (unsigned)gr < H)
            v = *reinterpret_cast<const float4*>(
                x + (size_t)(b * C + cg * 4 + ch) * HW + gr * W + (f - 1) * 4);
        uint2 hv = make_uint2(pk16(v.x, v.y), pk16(v.z, v.w));
        *reinterpret_cast<uint2*>(&xls[ch][row][f * 2]) = hv;   // 8B aligned
    }
    __syncthreads();

    // compute: tid = c*160 + hd*20 + q -> 4 outputs (wd = 4q..4q+3), 1 ch
    int q  = threadIdx.x % 20;
    int t3 = threadIdx.x / 20;                      // 0..31
    int hd = t3 & 7;
    int c  = t3 >> 3;                               // 0..3
    int px0 = hd * 80 + 4 * q;                      // local pixel in 640-group
    const uint* kb = ker_g + ((size_t)(b * 10 + hq) * 15) * 640;
    float a0 = 0.f, a1 = 0.f, a2 = 0.f, a3 = 0.f;
#pragma unroll
    for (int i = 0; i < 5; ++i) {
        int lr = 2 * hd + i;
        const uint* xrow = &xls[c][lr][4 * q];
        uint4 xa = *reinterpret_cast<const uint4*>(xrow);       // 16B aligned
        uint4 xb = *reinterpret_cast<const uint4*>(xrow + 4);
        uint xd[8] = {xa.x, xa.y, xa.z, xa.w, xb.x, xb.y, xb.z, xb.w};
        uint4 k0 = *reinterpret_cast<const uint4*>(kb + (i * 3 + 0) * 640 + px0);
        uint4 k1 = *reinterpret_cast<const uint4*>(kb + (i * 3 + 1) * 640 + px0);
        uint4 k2 = *reinterpret_cast<const uint4*>(kb + (i * 3 + 2) * 640 + px0);
        a0 = dot2f(xd[1], k0.x, a0); a0 = dot2f(xd[2], k1.x, a0); a0 = dot2f(xd[3], k2.x, a0);
        a1 = dot2f(xd[2], k0.y, a1); a1 = dot2f(xd[3], k1.y, a1); a1 = dot2f(xd[4], k2.y, a1);
        a2 = dot2f(xd[3], k0.z, a2); a2 = dot2f(xd[4], k1.z, a2); a2 = dot2f(xd[5], k2.z, a2);
        a3 = dot2f(xd[4], k0.w, a3); a3 = dot2f(xd[5], k1.w, a3); a3 = dot2f(xd[6], k2.w, a3);
    }
    *reinterpret_cast<float4*>(
        out + ((size_t)(b * C + cg * 4 + c) * HD + hq * 8 + hd) * WD + 4 * q) =
        make_float4(a0, a1, a2, a3);
}

extern "C" void kernel_launch(void* const* d_in, const int* in_sizes, int n_in,
                              void* d_out, int out_size, void* d_ws, size_t ws_size,
                              hipStream_t stream) {
    const float* x  = (const float*)d_in[0];
    const float* wc = (const float*)d_in[1];
    const float* we = (const float*)d_in[2];
    float* out = (float*)d_out;
    __hip_bfloat16* comp = (__hip_bfloat16*)d_ws;         // B*CM*HW bf16 = 6.55 MB
    uint* ker_g = (uint*)((char*)d_ws + (size_t)B * CM * HW * sizeof(__hip_bfloat16));
                                                          // B*10*15*640 u32 = 3.07 MB

    compress_k  <<<(B * HW / 4) / 64, 256, 0, stream>>>(x, wc, comp);    // 800 blocks
    encoder_k   <<<(B * HWD) / 64,    256, 0, stream>>>(comp, we, ker_g);// 800 blocks
    reassemble_k<<<B * 10 * 32,       640, 0, stream>>>(x, ker_g, out);  // 2560 blocks
}